// Round 10
// baseline (155.780 us; speedup 1.0000x reference)
//
#include <hip/hip_runtime.h>
#include <math.h>

#define NF 32
#define NN 4096
#define ND 64
#define NK 512

// loss = q_latent + 0.25 * e_latent = 1.25 * mean((q - x)^2)
#define LOSS_SCALE (1.25f / (float)(NF * NN * ND))
// rescue margin, tested in the PACKED-KEY domain: exact-score margin
// TAU=3e-4 (3-term split-bf16 err) + 2x col-pack trunc quantum
// (|s| <= ~3 -> q <= 1.3e-4): flag if s2' - s1' < 5.5e-4. Strictly
// conservative vs the exact-gap test (ties/collisions always flagged).
// Validated R8/R9 (passed, absmax 4.88e-4 unchanged).
#define RESCUE_TAU 5.5e-4f

typedef short bf16x8 __attribute__((ext_vector_type(8)));
typedef float f32x4 __attribute__((ext_vector_type(4)));

static __device__ __forceinline__ unsigned short f2bf_rne(float f) {
    unsigned int u = __float_as_uint(f);
    u += 0x7FFFu + ((u >> 16) & 1u);
    return (unsigned short)(u >> 16);
}
static __device__ __forceinline__ float bf2f(unsigned short h) {
    return __uint_as_float(((unsigned int)h) << 16);
}

// async global->LDS: 16B per lane, dest = wave-uniform base + lane*16
static __device__ __forceinline__ void gload_lds16(const void* g, void* l) {
    __builtin_amdgcn_global_load_lds(
        (const __attribute__((address_space(1))) unsigned int*)g,
        (__attribute__((address_space(3))) unsigned int*)l, 16, 0, 0);
}

// ---------------------------------------------------------------------------
// prep_w (R7, proven): LDS-transpose for coalesced w reads. Block =
// (f, 64-col k-group); phase 1 reads [64 d][64 k] tile with full-64B
// coalesced loads into LDS; phase 2 reads transposed, computes bf16 hi/lo
// split + 0.5||w||^2, writes wt/wh/wl coalesced. Zeroes loss slot. 256 blks.
// (R8 lesson: do NOT fuse this into argmin — device-scope fences/spin sync
// cost 5x the dispatch they save on CDNA4's non-coherent L2s.)
// ---------------------------------------------------------------------------
__global__ __launch_bounds__(256)
void vq_prep_w(const float* __restrict__ w, float* __restrict__ wt,
               unsigned short* __restrict__ wh, unsigned short* __restrict__ wl,
               float* __restrict__ w2h, float* __restrict__ loss_slot) {
    __shared__ float lds[64 * 65];        // +1 pad: transposed reads conflict-free
    const int t  = threadIdx.x;
    const int f  = blockIdx.x >> 3;
    const int k0 = (blockIdx.x & 7) * 64;
    const float* __restrict__ wf = w + (size_t)f * ND * NK;

    if (blockIdx.x == 0 && t == 0) *loss_slot = 0.0f;

    {   // phase 1: d = t>>2 (16 rows/wave), 4 float4 per thread
        const int d = t >> 2, qq = t & 3;
#pragma unroll
        for (int i = 0; i < 4; ++i) {
            const int c4 = qq + i * 4;    // float4 index within the 64-col row
            const float4 v = *(const float4*)(wf + (size_t)d * NK + k0 + c4 * 4);
            lds[d * 65 + c4 * 4 + 0] = v.x;
            lds[d * 65 + c4 * 4 + 1] = v.y;
            lds[d * 65 + c4 * 4 + 2] = v.z;
            lds[d * 65 + c4 * 4 + 3] = v.w;
        }
    }
    __syncthreads();

    // phase 2: thread owns (k = t>>2, d-range p*16..p*16+15)
    const int k = t >> 2, p = t & 3;
    float v[16];
    float s = 0.0f;
#pragma unroll
    for (int j = 0; j < 16; ++j) {
        v[j] = lds[(p * 16 + j) * 65 + k];
        s = fmaf(v[j], v[j], s);
    }
    s += __shfl_xor(s, 1, 64);            // 4 threads share one k
    s += __shfl_xor(s, 2, 64);
    if (p == 0) w2h[f * NK + k0 + k] = 0.5f * s;

    const size_t rowo = ((size_t)f * NK + k0 + k) * ND + p * 16;
    unsigned short hh[16], ll[16];
#pragma unroll
    for (int j = 0; j < 16; ++j) {
        hh[j] = f2bf_rne(v[j]);
        ll[j] = f2bf_rne(v[j] - bf2f(hh[j]));
    }
#pragma unroll
    for (int i = 0; i < 4; ++i) {
        *(float4*)(wt + rowo + i * 4) =
            make_float4(v[i*4+0], v[i*4+1], v[i*4+2], v[i*4+3]);
        *(ushort4*)(wh + rowo + i * 4) =
            make_ushort4(hh[i*4+0], hh[i*4+1], hh[i*4+2], hh[i*4+3]);
        *(ushort4*)(wl + rowo + i * 4) =
            make_ushort4(ll[i*4+0], ll[i*4+1], ll[i*4+2], ll[i*4+3]);
    }
}

// ---------------------------------------------------------------------------
// argmin FUSED v10 = R9 (146us total, best known) + two local changes:
//  1) SPLIT ACCUMULATOR CHAINS: the 6 dependent MFMAs per (tl,mt) group
//     (~150-200 cyc serial latency) become two independent 3-deep chains
//     (cA init w2, cB init 0; one f32x4 add at the end). Halves per-group
//     MFMA critical path; +4 VGPR/group under the 128-VGPR (256,4) cap.
//  2) x WRITE-BACK FOR GATHER: after the loop, bstage (32KB) is dead =
//     exactly 128x64 fp32. Reconstruct x from the A-frags
//     (x = -(hi+lo), error ~2^-18 relative: the hi-subtract was exact by
//     Sterbenz, only lo-rounding survives) and ds_write it XOR-swizzled
//     (16B chunk index ^= row&15 -> ~2-way bank aliasing = free). The
//     gather then reads x~ from LDS -- used ONLY for the loss mean, where
//     4e-6-relative error washes out; out = q needs no x. RESCUE KEEPS
//     EXACT GLOBAL x (argmin decisions must stay exact: near-tie flips
//     would blow absmax). Saves the 32MB L3-hit x re-read in the tail.
// Everything else identical to R9.
// ---------------------------------------------------------------------------
__global__ __launch_bounds__(256, 4)
void vq_argmin(const float* __restrict__ x_in,
               const unsigned short* __restrict__ wh,
               const unsigned short* __restrict__ wl,
               const float* __restrict__ wt,
               const float* __restrict__ w2h,
               float* __restrict__ out,
               float* __restrict__ loss_slot) {
    const int b    = blockIdx.x;          // [0, 1024)
    const int j    = b >> 3;              // [0, 128)
    const int f    = (b & 7) * 4 + (j & 3);
    const int xt   = j >> 2;              // [0, 32)
    const int tid  = threadIdx.x;
    const int wave = tid >> 6;
    const int lane = tid & 63;
    const int lc   = lane & 15;
    const int q    = lane >> 4;
    const int n0   = xt * 128 + wave * 32;   // wave's private 32 rows
    const int g0b  = f * NN + xt * 128;      // block's global row base

    __shared__ float w2s[NK];                                 // 2 KB
    __shared__ __align__(16) unsigned short bstage[2][8192];  // 2 x 16 KB
    __shared__ unsigned int lds_key[128];                     // 512 B
    __shared__ unsigned char lds_flag[128];                   // 128 B
    __shared__ float wsum[4];

    for (int t = tid; t < NK; t += 256) w2s[t] = w2h[f * NK + t];

    // ---- A-frags: 32 rows' (-x), split to bf16 hi/lo in-register.
    bf16x8 ah[2][2], al[2][2];
    const float* __restrict__ xbase = x_in + ((size_t)f * NN + n0 + lc) * ND;
#pragma unroll
    for (int mt = 0; mt < 2; ++mt) {
#pragma unroll
        for (int s = 0; s < 2; ++s) {
            const float* p = xbase + mt * 16 * ND + s * 32 + q * 8;
            float4 u0 = *(const float4*)(p);
            float4 u1 = *(const float4*)(p + 4);
            float xv[8] = {-u0.x, -u0.y, -u0.z, -u0.w, -u1.x, -u1.y, -u1.z, -u1.w};
            bf16x8 hh, ll;
#pragma unroll
            for (int jj = 0; jj < 8; ++jj) {
                unsigned short hb = f2bf_rne(xv[jj]);
                unsigned short lb = f2bf_rne(xv[jj] - bf2f(hb));
                hh[jj] = (short)hb;
                ll[jj] = (short)lb;
            }
            ah[mt][s] = hh;
            al[mt][s] = ll;
        }
    }

    const unsigned short* __restrict__ whf = wh + (size_t)f * NK * ND;
    const unsigned short* __restrict__ wlf = wl + (size_t)f * NK * ND;

    // slim 2-channel packed top-2: k1 = min key, k2 = 2nd-min key
    float k1[8], k2[8];
#pragma unroll
    for (int ri = 0; ri < 8; ++ri) { k1[ri] = INFINITY; k2[ri] = INFINITY; }

    // ---- stage 64-col supertile st into bstage[pb]: 16 chunks of 1KB,
    // 4 per wave. chunk c: tl = c>>2 (16-col tile), sg = (c>>1)&1 (d-half),
    // c&1 = lo/hi. lane-linear dest (global_load_lds requirement).
#define STAGE(st, pb) do {                                                  \
    _Pragma("unroll")                                                       \
    for (int rep = 0; rep < 4; ++rep) {                                     \
        const int c  = wave * 4 + rep;                                      \
        const int tl = c >> 2;                                              \
        const int sg = (c >> 1) & 1;                                        \
        const unsigned short* src = ((c & 1) ? wlf : whf) +                 \
            (size_t)((st) * 64 + tl * 16 + lc) * ND + q * 8 + sg * 32;      \
        gload_lds16(src, &bstage[pb][c * 512]);                             \
    }                                                                       \
} while (0)

    STAGE(0, 0);

    for (int st = 0; st < 8; ++st) {
        __syncthreads();                 // drains this st's loads (vmcnt)
        if (st < 7) STAGE(st + 1, (st + 1) & 1);
        const unsigned short* __restrict__ bb = &bstage[st & 1][0];

#pragma unroll
        for (int tl = 0; tl < 4; ++tl) {
            const int col = st * 64 + tl * 16 + lc;
            bf16x8 bh0 = *(const bf16x8*)(bb + (tl * 4 + 0) * 512 + lane * 8);
            bf16x8 bl0 = *(const bf16x8*)(bb + (tl * 4 + 1) * 512 + lane * 8);
            bf16x8 bh1 = *(const bf16x8*)(bb + (tl * 4 + 2) * 512 + lane * 8);
            bf16x8 bl1 = *(const bf16x8*)(bb + (tl * 4 + 3) * 512 + lane * 8);
            const float w2 = w2s[col];
#pragma unroll
            for (int mt = 0; mt < 2; ++mt) {
                // two independent 3-deep MFMA chains (halved dep latency)
                f32x4 cA = {w2, w2, w2, w2};
                f32x4 cB = {0.0f, 0.0f, 0.0f, 0.0f};
                cA = __builtin_amdgcn_mfma_f32_16x16x32_bf16(ah[mt][0], bh0, cA, 0, 0, 0);
                cB = __builtin_amdgcn_mfma_f32_16x16x32_bf16(ah[mt][1], bh1, cB, 0, 0, 0);
                cA = __builtin_amdgcn_mfma_f32_16x16x32_bf16(ah[mt][0], bl0, cA, 0, 0, 0);
                cB = __builtin_amdgcn_mfma_f32_16x16x32_bf16(ah[mt][1], bl1, cB, 0, 0, 0);
                cA = __builtin_amdgcn_mfma_f32_16x16x32_bf16(al[mt][0], bh0, cA, 0, 0, 0);
                cB = __builtin_amdgcn_mfma_f32_16x16x32_bf16(al[mt][1], bh1, cB, 0, 0, 0);
#pragma unroll
                for (int r = 0; r < 4; ++r) {
                    const int ri = mt * 4 + r;
                    const float sc = cA[r] + cB[r];
                    // packed key: col in low 9 mantissa bits; 3 VALU/score
                    const float key = __uint_as_float(
                        (__float_as_uint(sc) & 0xFFFFFE00u) | (unsigned int)col);
                    k2[ri] = __builtin_amdgcn_fmed3f(key, k1[ri], k2[ri]);
                    k1[ri] = fminf(key, k1[ri]);
                }
            }
        }
    }

    // ---- all waves done reading bstage; reuse it as the x~ buffer ----
    __syncthreads();
    {
        // x~ = -(hi+lo) (error ~2^-18 rel). Layout: [128 rows][16 chunks of
        // 16B], chunk index XOR-swizzled by (row&15) -> writes and reads
        // spread across all banks (~2-way aliasing = free, G4/m136).
        float* __restrict__ xs = (float*)&bstage[0][0];
#pragma unroll
        for (int mt = 0; mt < 2; ++mt) {
#pragma unroll
            for (int s = 0; s < 2; ++s) {
                const int row = wave * 32 + mt * 16 + lc;
                const int cc0 = s * 8 + q * 2;
#pragma unroll
                for (int t2 = 0; t2 < 2; ++t2) {
                    const int cc = cc0 + t2;
                    float4 v;
                    v.x = -(bf2f((unsigned short)ah[mt][s][t2*4+0]) +
                            bf2f((unsigned short)al[mt][s][t2*4+0]));
                    v.y = -(bf2f((unsigned short)ah[mt][s][t2*4+1]) +
                            bf2f((unsigned short)al[mt][s][t2*4+1]));
                    v.z = -(bf2f((unsigned short)ah[mt][s][t2*4+2]) +
                            bf2f((unsigned short)al[mt][s][t2*4+2]));
                    v.w = -(bf2f((unsigned short)ah[mt][s][t2*4+3]) +
                            bf2f((unsigned short)al[mt][s][t2*4+3]));
                    *(float4*)(xs + row * 64 + ((cc ^ (row & 15)) << 2)) = v;
                }
            }
        }
    }

    // ---- merge packed top-2 across the 16 lanes holding each row ----
#pragma unroll
    for (int ri = 0; ri < 8; ++ri) {
        float a1 = k1[ri], a2 = k2[ri];
#pragma unroll
        for (int off = 1; off < 16; off <<= 1) {
            const float b1 = __shfl_xor(a1, off, 64);
            const float b2 = __shfl_xor(a2, off, 64);
            a2 = fminf(fminf(a2, b2), fmaxf(a1, b1));
            a1 = fminf(a1, b1);
        }
        k1[ri] = a1; k2[ri] = a2;
    }

    if (lc == 0) {
#pragma unroll
        for (int mt = 0; mt < 2; ++mt) {
#pragma unroll
            for (int r = 0; r < 4; ++r) {
                const int ri = mt * 4 + r;
                const int lr = wave * 32 + mt * 16 + q * 4 + r;  // block-local row
                const unsigned int u1 = __float_as_uint(k1[ri]);
                const unsigned int u2 = __float_as_uint(k2[ri]);
                lds_key[lr] = u1 & 0x1FFu;
                const float s1 = __uint_as_float(u1 & 0xFFFFFE00u);
                const float s2 = __uint_as_float(u2 & 0xFFFFFE00u);
                lds_flag[lr] = (s2 - s1 < RESCUE_TAU) ? 1 : 0;
            }
        }
    }
    __syncthreads();

    // ---- wave-local exact rescue of flagged rows (EXACT global x) ----
    {
        const int lr32 = wave * 32 + (lane & 31);
        const int fl = (lane < 32) ? lds_flag[lr32] : 0;
        unsigned long long mm = __ballot(fl != 0);
        const float* __restrict__ wtf = wt + (size_t)f * NK * ND;
        while (mm) {
            const int r = __ffsll(mm) - 1;
            mm &= mm - 1;
            const int grow = g0b + wave * 32 + r;
            const float* __restrict__ xr = x_in + (size_t)grow * ND;
            unsigned long long best = 0xFFFFFFFFFFFFFFFFULL;
#pragma unroll 1
            for (int jj = 0; jj < 8; ++jj) {
                const int col = jj * 64 + lane;
                const float* __restrict__ wr = wtf + (size_t)col * ND;
                float t = w2s[col];
#pragma unroll
                for (int d = 0; d < ND; d += 4) {
                    float4 xv = *(const float4*)(xr + d);   // broadcast
                    float4 wv = *(const float4*)(wr + d);
                    t = fmaf(-xv.x, wv.x, t);
                    t = fmaf(-xv.y, wv.y, t);
                    t = fmaf(-xv.z, wv.z, t);
                    t = fmaf(-xv.w, wv.w, t);
                }
                unsigned int u = __float_as_uint(t);
                u ^= (unsigned int)((int)u >> 31) | 0x80000000u;
                const unsigned long long key =
                    ((unsigned long long)u << 32) | (unsigned int)col;
                best = key < best ? key : best;
            }
#pragma unroll
            for (int off = 32; off > 0; off >>= 1) {
                const unsigned long long o = __shfl_xor(best, off, 64);
                best = o < best ? o : best;
            }
            if (lane == 0) lds_key[wave * 32 + r] = (unsigned int)(best & 0x1FFu);
        }
    }
    __syncthreads();

    // ---- gather + loss: 2 threads per row (32 floats each); x~ from LDS ----
    {
        const int row_l = tid >> 1;
        const int part  = tid & 1;
        const int grow  = g0b + row_l;
        const unsigned int k = lds_key[row_l];
        const float* __restrict__ q32 = wt + ((size_t)f * NK + k) * ND + part * 32;
        const float* __restrict__ xs  = (const float*)&bstage[0][0];
        float* __restrict__ o32       = out + (size_t)grow * ND + part * 32;

        float lsum = 0.0f;
#pragma unroll
        for (int jj = 0; jj < 8; ++jj) {
            const int cc = part * 8 + jj;
            float4 qv = *(const float4*)(q32 + 4 * jj);
            float4 xv = *(const float4*)(xs + row_l * 64 + ((cc ^ (row_l & 15)) << 2));
            const float dx0 = qv.x - xv.x;
            const float dx1 = qv.y - xv.y;
            const float dx2 = qv.z - xv.z;
            const float dx3 = qv.w - xv.w;
            lsum = fmaf(dx0, dx0, lsum);
            lsum = fmaf(dx1, dx1, lsum);
            lsum = fmaf(dx2, dx2, lsum);
            lsum = fmaf(dx3, dx3, lsum);
            *(float4*)(o32 + 4 * jj) = qv;
        }

#pragma unroll
        for (int off = 32; off > 0; off >>= 1) {
            lsum += __shfl_down(lsum, off, 64);
        }
        if ((tid & 63) == 0) wsum[tid >> 6] = lsum;
        __syncthreads();
        if (tid == 0) {
            atomicAdd(loss_slot,
                      (wsum[0] + wsum[1] + wsum[2] + wsum[3]) * LOSS_SCALE);
        }
    }
}

extern "C" void kernel_launch(void* const* d_in, const int* in_sizes, int n_in,
                              void* d_out, int out_size, void* d_ws, size_t ws_size,
                              hipStream_t stream) {
    const float* x_in = (const float*)d_in[0];  // [F, N, D] fp32
    const float* w    = (const float*)d_in[1];  // [F, D, K] fp32
    float* out        = (float*)d_out;          // [F*N*D] output then [1] loss

    float* wt  = (float*)d_ws;                                   // 4 MB
    float* w2h = wt + (size_t)NF * NK * ND;                      // 64 KB
    unsigned short* wh = (unsigned short*)(w2h + NF * NK);       // 2 MB
    unsigned short* wl = wh + (size_t)NF * NK * ND;              // 2 MB

    float* loss_slot = out + (size_t)NF * NN * ND;

    vq_prep_w<<<NF * 8, 256, 0, stream>>>(w, wt, wh, wl, w2h, loss_slot);

    vq_argmin<<<NF * NN / 128, 256, 0, stream>>>(x_in, wh, wl, wt, w2h,
                                                 out, loss_slot);
}